// Round 9
// baseline (503.671 us; speedup 1.0000x reference)
//
#include <hip/hip_runtime.h>

#define NN 100000
#define NE 1600000
#define DD 128
#define BM 64
#define NPB 256                   // nodes per bucket
#define NBUCK 391                 // ceil(NN / NPB)
#define ECHUNK 8192
#define NBLK_PART 196             // ceil(NE / ECHUNK)
#define CAP 8192                  // LDS staging capacity (mean bucket = 4096 edges)
#define CVX_BLK 512
#define CVW_BLK 384

typedef __attribute__((ext_vector_type(2))) float f32x2;
typedef __attribute__((ext_vector_type(4))) float f32x4;
typedef __attribute__((ext_vector_type(8))) short bf16x8;

__device__ inline unsigned short f2bf(float f) {
    unsigned int x = __builtin_bit_cast(unsigned int, f);
    unsigned int r = x + 0x7fffu + ((x >> 16) & 1u);
    return (unsigned short)(r >> 16);
}
__device__ inline unsigned int packbf(float a, float b) {
    return (unsigned int)f2bf(a) | ((unsigned int)f2bf(b) << 16);
}
// fp8 e4m3 pack/unpack via gfx950 HW converts (codec is self-consistent)
__device__ inline unsigned int pk_fp8x4(float a, float b, float c, float d) {
    int v = 0;
    v = __builtin_amdgcn_cvt_pk_fp8_f32(a, b, v, false);
    v = __builtin_amdgcn_cvt_pk_fp8_f32(c, d, v, true);
    return (unsigned int)v;
}
__device__ inline f32x2 upk_fp8_lo(unsigned int v) {
    return __builtin_amdgcn_cvt_pk_f32_fp8((int)v, false);
}
__device__ inline f32x2 upk_fp8_hi(unsigned int v) {
    return __builtin_amdgcn_cvt_pk_f32_fp8((int)v, true);
}

// ---------------- fused prep: conv_x (fp8 only) + conv_w + bucket_hist ----------------

__global__ __launch_bounds__(256) void prep_kernel(
    const float* __restrict__ x, unsigned int* __restrict__ xf8,
    const float* __restrict__ w0, const float* __restrict__ w1,
    const float* __restrict__ w2, const float* __restrict__ w3,
    const float* __restrict__ w4, const float* __restrict__ w5,
    unsigned short* __restrict__ wtall,
    const int* __restrict__ row, int* __restrict__ gcnt) {
    __shared__ int cnt[NBUCK];
    const int b = blockIdx.x;
    if (b < CVX_BLK) {
        int i = b * 256 + threadIdx.x;
        const int n4 = NN * DD / 4;
        for (; i < n4; i += CVX_BLK * 256) {
            float4 v = reinterpret_cast<const float4*>(x)[i];
            xf8[i] = pk_fp8x4(v.x, v.y, v.z, v.w);
        }
    } else if (b < CVX_BLK + CVW_BLK) {
        int t = (b - CVX_BLK) * 256 + threadIdx.x;   // 0 .. 6*16384-1
        int i = t >> 14;
        int r = t & 16383;
        const float* W = (i == 0) ? w0 : (i == 1) ? w1 : (i == 2) ? w2
                        : (i == 3) ? w3 : (i == 4) ? w4 : w5;
        int c = r >> 7, k = r & 127;
        wtall[t] = f2bf(W[k * DD + c]);
    } else {
        for (int i = threadIdx.x; i < NBUCK; i += 256) cnt[i] = 0;
        __syncthreads();
        int base = (b - CVX_BLK - CVW_BLK) * ECHUNK;
        int end = base + ECHUNK; if (end > NE) end = NE;
        for (int i = base + threadIdx.x; i < end; i += 256)
            atomicAdd(&cnt[row[i] >> 8], 1);
        __syncthreads();
        for (int i = threadIdx.x; i < NBUCK; i += 256) {
            int c = cnt[i];
            if (c) atomicAdd(&gcnt[i], c);
        }
    }
}

// ---------------- bucketed CSR build ----------------

__global__ __launch_bounds__(512) void bucket_scan(const int* __restrict__ gcnt,
                                                   int* __restrict__ gbase) {
    __shared__ int sm[512];
    int t = threadIdx.x;
    sm[t] = (t < NBUCK) ? gcnt[t] : 0;
    __syncthreads();
    for (int off = 1; off < 512; off <<= 1) {
        int add = (t >= off) ? sm[t - off] : 0;
        __syncthreads();
        sm[t] += add;
        __syncthreads();
    }
    if (t < NBUCK) gbase[t + 1] = sm[t];
    if (t == 0) gbase[0] = 0;
}

// edges packed as (col<<8)|(row&255): row-in-bucket fits 8 bits, col fits 17
__global__ __launch_bounds__(256) void bucket_scatter(const int* __restrict__ row,
                                                      const int* __restrict__ col,
                                                      const int* __restrict__ gbase,
                                                      int* __restrict__ gcursor,
                                                      unsigned int* __restrict__ ebuf) {
    __shared__ int cnt[NBUCK];
    __shared__ int base[NBUCK];
    for (int i = threadIdx.x; i < NBUCK; i += 256) cnt[i] = 0;
    __syncthreads();
    int cbase = blockIdx.x * ECHUNK;
    int cend = cbase + ECHUNK; if (cend > NE) cend = NE;
    for (int i = cbase + threadIdx.x; i < cend; i += 256)
        atomicAdd(&cnt[row[i] >> 8], 1);
    __syncthreads();
    for (int i = threadIdx.x; i < NBUCK; i += 256) {
        int c = cnt[i];
        cnt[i] = 0;
        base[i] = c ? (gbase[i] + atomicAdd(&gcursor[i], c)) : 0;
    }
    __syncthreads();
    for (int i = cbase + threadIdx.x; i < cend; i += 256) {
        int r = row[i], c = col[i];
        int b = r >> 8;
        int k = atomicAdd(&cnt[b], 1);
        ebuf[base[b] + k] = ((unsigned)c << 8) | ((unsigned)r & 255u);
    }
}

__global__ __launch_bounds__(256) void csr_build(const unsigned int* __restrict__ ebuf,
                                                 const int* __restrict__ gbase,
                                                 int* __restrict__ offs,
                                                 int* __restrict__ csr_col) {
    __shared__ int dcnt[NPB];
    __shared__ int doff[NPB];
    __shared__ int sm[NPB];
    __shared__ int stage[CAP];
    const int b = blockIdx.x;
    const int es = gbase[b], ee = gbase[b + 1];
    const int m = ee - es;
    const int t = threadIdx.x;
    const int nbase = b * NPB;

    dcnt[t] = 0;
    __syncthreads();
    for (int i = es + t; i < ee; i += 256) {
        int ln = (int)(ebuf[i] & 255u);
        atomicAdd(&dcnt[ln], 1);
    }
    __syncthreads();
    sm[t] = dcnt[t];
    __syncthreads();
    for (int off = 1; off < 256; off <<= 1) {
        int add = (t >= off) ? sm[t - off] : 0;
        __syncthreads();
        sm[t] += add;
        __syncthreads();
    }
    doff[t] = sm[t] - dcnt[t];
    int node = nbase + t;
    if (node < NN) offs[node + 1] = es + sm[t];
    if (b == 0 && t == 0) offs[0] = 0;
    dcnt[t] = 0;
    __syncthreads();

    if (m <= CAP) {
        for (int i = es + t; i < ee; i += 256) {
            unsigned e = ebuf[i];
            int ln = (int)(e & 255u);
            int k = atomicAdd(&dcnt[ln], 1);
            stage[doff[ln] + k] = (int)(e >> 8);
        }
        __syncthreads();
        for (int i = t; i < m; i += 256) csr_col[es + i] = stage[i];
    } else {
        for (int i = es + t; i < ee; i += 256) {
            unsigned e = ebuf[i];
            int ln = (int)(e & 255u);
            int k = atomicAdd(&dcnt[ln], 1);
            csr_col[es + doff[ln] + k] = (int)(e >> 8);
        }
    }
}

// ---------------- fused layer: fp8 gather-aggregate + dual GEMM + epilogue ----------------

// per 64-row tile: gather-mean fp8 neighbors (8 lanes x 16B per node, padded
// 8-wide masked batches) into a swizzled bf16 A LDS tile (16KB); H self-term
// fragments rebuilt in-register from the fp32 source (x or previous out, NT
// loads, L3-warm); MFMA relu(A@Wl + H@Wr + b); epilogue streams out via two
// 32-row passes through the same 16KB LDS.
__global__ __launch_bounds__(256, 6) void fused_layer(
    const float* __restrict__ hsrc,                  // fp32 h source (x or prev out)
    const unsigned int* __restrict__ f8,             // fp8 h (gather table), dword-viewed
    const int* __restrict__ offs, const int* __restrict__ csr_col,
    const unsigned short* __restrict__ WlT, const unsigned short* __restrict__ WrT,
    const float* __restrict__ bias, float* __restrict__ out,
    unsigned int* __restrict__ f8n) {
    __shared__ uint4 smem4[1024];            // 16KB: A tile, reused as fp32 half-out tile
    char* AldsB = (char*)smem4;
    const int row0 = blockIdx.x * BM;
    const int tid = threadIdx.x;
    const int w = tid >> 6, l = tid & 63;
    const int wr = w & 1, wc = w >> 1;
    const int lrow = l & 15, lg = l >> 4;

    // 1) fp8 gather-aggregate: 8 lanes per node (16B/lane), 2 rows per group,
    //    padded 8-wide batches (clamped index + AND-mask; fp8 0x00 == +0.0)
    const int grp = tid >> 3, lane = tid & 7;
    const uint4* f84 = reinterpret_cast<const uint4*>(f8);
#pragma unroll
    for (int i = 0; i < 2; ++i) {
        const int rloc = grp * 2 + i;
        const int node = row0 + rloc;
        f32x2 a[8];
#pragma unroll
        for (int k = 0; k < 8; ++k) a[k] = (f32x2){0.f, 0.f};
        float inv = 0.0f;
        if (node < NN) {
            const int s = offs[node], e = offs[node + 1];
            const int emax = e - 1;
            for (int p = s; p < e; p += 8) {
                uint4 v[8];
#pragma unroll
                for (int q = 0; q < 8; ++q) {
                    int idx = p + q;
                    int ci = idx < emax ? idx : emax;
                    int c = __builtin_nontemporal_load(csr_col + ci);
                    v[q] = f84[(size_t)c * 8 + lane];
                    unsigned msk = (idx < e) ? 0xFFFFFFFFu : 0u;
                    v[q].x &= msk; v[q].y &= msk; v[q].z &= msk; v[q].w &= msk;
                }
#pragma unroll
                for (int q = 0; q < 8; ++q) {
                    a[0] += upk_fp8_lo(v[q].x); a[1] += upk_fp8_hi(v[q].x);
                    a[2] += upk_fp8_lo(v[q].y); a[3] += upk_fp8_hi(v[q].y);
                    a[4] += upk_fp8_lo(v[q].z); a[5] += upk_fp8_hi(v[q].z);
                    a[6] += upk_fp8_lo(v[q].w); a[7] += upk_fp8_hi(v[q].w);
                }
            }
            inv = (e > s) ? (1.0f / (float)(e - s)) : 0.0f;
        }
        uint4 o0, o1;
        o0.x = packbf(a[0][0] * inv, a[0][1] * inv);
        o0.y = packbf(a[1][0] * inv, a[1][1] * inv);
        o0.z = packbf(a[2][0] * inv, a[2][1] * inv);
        o0.w = packbf(a[3][0] * inv, a[3][1] * inv);
        o1.x = packbf(a[4][0] * inv, a[4][1] * inv);
        o1.y = packbf(a[5][0] * inv, a[5][1] * inv);
        o1.z = packbf(a[6][0] * inv, a[6][1] * inv);
        o1.w = packbf(a[7][0] * inv, a[7][1] * inv);
        const int sw = (rloc & 7) << 4;
        const int rbase = rloc << 8;
        *reinterpret_cast<uint4*>(AldsB + rbase + ((lane * 32) ^ sw)) = o0;
        *reinterpret_cast<uint4*>(AldsB + rbase + ((lane * 32 + 16) ^ sw)) = o1;
    }

    // 2) H fragments from fp32 source, converted to bf16 in-register
    //    (issued before the barrier: latency overlaps other waves' gather)
    bf16x8 aH[2][4];
#pragma unroll
    for (int m = 0; m < 2; ++m) {
        int gr = row0 + wr * 32 + m * 16 + lrow;
        if (gr >= NN) gr = NN - 1;
        const float* hrow = hsrc + (size_t)gr * DD;
#pragma unroll
        for (int kb = 0; kb < 4; ++kb) {
            f32x4 v0 = __builtin_nontemporal_load(
                reinterpret_cast<const f32x4*>(hrow + kb * 32 + lg * 8));
            f32x4 v1 = __builtin_nontemporal_load(
                reinterpret_cast<const f32x4*>(hrow + kb * 32 + lg * 8 + 4));
            uint4 pk;
            pk.x = packbf(v0[0], v0[1]);
            pk.y = packbf(v0[2], v0[3]);
            pk.z = packbf(v1[0], v1[1]);
            pk.w = packbf(v1[2], v1[3]);
            aH[m][kb] = __builtin_bit_cast(bf16x8, pk);
        }
    }
    __syncthreads();

    // 3) MFMA: acc = A@Wl + H@Wr
    f32x4 acc[2][4];
#pragma unroll
    for (int m = 0; m < 2; ++m)
#pragma unroll
        for (int n = 0; n < 4; ++n) acc[m][n] = (f32x4){0.f, 0.f, 0.f, 0.f};

    float bv[4];
#pragma unroll
    for (int n = 0; n < 4; ++n) bv[n] = bias[wc * 64 + n * 16 + lrow];

#pragma unroll
    for (int kb = 0; kb < 4; ++kb) {
        const int kbyte = kb * 64 + lg * 16;
        bf16x8 aA[2];
#pragma unroll
        for (int m = 0; m < 2; ++m) {
            int rloc = wr * 32 + m * 16 + lrow;
            int off = (rloc << 8) + kbyte;
            off ^= (rloc & 7) << 4;
            aA[m] = *reinterpret_cast<const bf16x8*>(AldsB + off);
        }
        bf16x8 bL[4], bR[4];
#pragma unroll
        for (int n = 0; n < 4; ++n) {
            size_t woff = ((size_t)(wc * 64 + n * 16 + lrow) << 7) + kb * 32 + lg * 8;
            bL[n] = *reinterpret_cast<const bf16x8*>(WlT + woff);
            bR[n] = *reinterpret_cast<const bf16x8*>(WrT + woff);
        }
#pragma unroll
        for (int m = 0; m < 2; ++m)
#pragma unroll
            for (int n = 0; n < 4; ++n) {
                acc[m][n] = __builtin_amdgcn_mfma_f32_16x16x32_bf16(aA[m], bL[n], acc[m][n], 0, 0, 0);
                acc[m][n] = __builtin_amdgcn_mfma_f32_16x16x32_bf16(aH[m][kb], bR[n], acc[m][n], 0, 0, 0);
            }
    }

    // 4) epilogue: two 32-row passes through the 16KB LDS, coalesced streams
    __syncthreads();
    float* otile = (float*)smem4;
#pragma unroll
    for (int half = 0; half < 2; ++half) {
        if (wr == half) {
#pragma unroll
            for (int m = 0; m < 2; ++m) {
                int rb = m * 16 + lg * 4;
#pragma unroll
                for (int n = 0; n < 4; ++n) {
                    int c = wc * 64 + n * 16 + lrow;
#pragma unroll
                    for (int j = 0; j < 4; ++j)
                        otile[(rb + j) * DD + c] = fmaxf(acc[m][n][j] + bv[n], 0.0f);
                }
            }
        }
        __syncthreads();
        const f32x4* t4 = (const f32x4*)smem4;
#pragma unroll
        for (int it = 0; it < 4; ++it) {
            int idx = it * 256 + tid;        // 1024 f32x4 units in 32x128 tile
            int r = idx >> 5;
            int gr = row0 + half * 32 + r;
            if (gr < NN) {
                f32x4 v = t4[idx];
                __builtin_nontemporal_store(v, (f32x4*)out + (size_t)gr * 32 + (idx & 31));
                if (f8n)
                    f8n[(size_t)gr * 32 + (idx & 31)] = pk_fp8x4(v[0], v[1], v[2], v[3]);
            }
        }
        __syncthreads();
    }
}

extern "C" void kernel_launch(void* const* d_in, const int* in_sizes, int n_in,
                              void* d_out, int out_size, void* d_ws, size_t ws_size,
                              hipStream_t stream) {
    const float* x = (const float*)d_in[0];
    const int* ei = (const int*)d_in[1];
    const int* row = ei;        // dst
    const int* col = ei + NE;   // src
    const float* Wl[3] = {(const float*)d_in[2], (const float*)d_in[5], (const float*)d_in[8]};
    const float* Wr[3] = {(const float*)d_in[3], (const float*)d_in[6], (const float*)d_in[9]};
    const float* bb[3] = {(const float*)d_in[4], (const float*)d_in[7], (const float*)d_in[10]};
    float* out = (float*)d_out;

    char* ws = (char*)d_ws;
    auto carve = [&](size_t bytes) {
        char* p = ws;
        ws += (bytes + 255) & ~(size_t)255;
        return p;
    };
    unsigned int* f8a = (unsigned int*)carve((size_t)NN * DD);      // fp8 tables, 12.8 MB each
    unsigned int* f8b = (unsigned int*)carve((size_t)NN * DD);
    unsigned short* wtall = (unsigned short*)carve((size_t)6 * DD * DD * 2);
    int* gcnt    = (int*)carve((size_t)2 * NBUCK * sizeof(int));  // gcnt + gcursor
    int* gcursor = gcnt + NBUCK;
    int* gbase   = (int*)carve((size_t)(NBUCK + 1) * sizeof(int));
    int* offs    = (int*)carve((size_t)(NN + 1) * sizeof(int));
    unsigned int* ebuf = (unsigned int*)carve((size_t)NE * sizeof(unsigned int)); // 6.4 MB
    int* csr_col = (int*)carve((size_t)NE * sizeof(int));         // 6.4 MB

    hipMemsetAsync(gcnt, 0, (size_t)2 * NBUCK * sizeof(int), stream);

    prep_kernel<<<CVX_BLK + CVW_BLK + NBLK_PART, 256, 0, stream>>>(
        x, f8a, Wl[0], Wr[0], Wl[1], Wr[1], Wl[2], Wr[2], wtall, row, gcnt);
    bucket_scan<<<1, 512, 0, stream>>>(gcnt, gbase);
    bucket_scatter<<<NBLK_PART, 256, 0, stream>>>(row, col, gbase, gcursor, ebuf);
    csr_build<<<NBUCK, 256, 0, stream>>>(ebuf, gbase, offs, csr_col);

    const int ngrid = (NN + BM - 1) / BM;   // 1563

    const float* hsrc = x;
    unsigned int* f8in = f8a;
    unsigned int* f8out = f8b;
    for (int lyr = 0; lyr < 3; ++lyr) {
        float* o = out + (size_t)lyr * NN * DD;
        fused_layer<<<ngrid, 256, 0, stream>>>(
            hsrc, f8in, offs, csr_col,
            wtall + (size_t)2 * lyr * DD * DD, wtall + (size_t)(2 * lyr + 1) * DD * DD,
            bb[lyr], o,
            (lyr < 2) ? f8out : (unsigned int*)nullptr);
        hsrc = o;
        unsigned int* t8 = f8in; f8in = f8out; f8out = t8;
    }
}

// Round 10
// 307.689 us; speedup vs baseline: 1.6369x; 1.6369x over previous
//
#include <hip/hip_runtime.h>

#define NN 100000
#define NE 1600000
#define DD 128
#define BM 64
#define NPB 256                   // nodes per bucket
#define NBUCK 391                 // ceil(NN / NPB)
#define ECHUNK 8192
#define NBLK_PART 196             // ceil(NE / ECHUNK)
#define CAP 8192                  // LDS staging capacity (mean bucket = 4096 edges)
#define CVX_BLK 800
#define CVW_BLK 384

typedef __attribute__((ext_vector_type(2))) float f32x2;
typedef __attribute__((ext_vector_type(4))) float f32x4;
typedef __attribute__((ext_vector_type(8))) short bf16x8;

__device__ inline unsigned short f2bf(float f) {
    unsigned int x = __builtin_bit_cast(unsigned int, f);
    unsigned int r = x + 0x7fffu + ((x >> 16) & 1u);
    return (unsigned short)(r >> 16);
}
__device__ inline unsigned int packbf(float a, float b) {
    return (unsigned int)f2bf(a) | ((unsigned int)f2bf(b) << 16);
}
// fp8 e4m3 pack/unpack via gfx950 HW converts (codec is self-consistent)
__device__ inline unsigned int pk_fp8x4(float a, float b, float c, float d) {
    int v = 0;
    v = __builtin_amdgcn_cvt_pk_fp8_f32(a, b, v, false);
    v = __builtin_amdgcn_cvt_pk_fp8_f32(c, d, v, true);
    return (unsigned int)v;
}
__device__ inline f32x2 upk_fp8_lo(unsigned int v) {
    return __builtin_amdgcn_cvt_pk_f32_fp8((int)v, false);
}
__device__ inline f32x2 upk_fp8_hi(unsigned int v) {
    return __builtin_amdgcn_cvt_pk_f32_fp8((int)v, true);
}

// ---------------- fused prep: conv_x (bf16 + fp8) + conv_w + bucket_hist ----------------

__global__ __launch_bounds__(256) void prep_kernel(
    const float* __restrict__ x, unsigned short* __restrict__ xb,
    unsigned int* __restrict__ xf8,
    const float* __restrict__ w0, const float* __restrict__ w1,
    const float* __restrict__ w2, const float* __restrict__ w3,
    const float* __restrict__ w4, const float* __restrict__ w5,
    unsigned short* __restrict__ wtall,
    const int* __restrict__ row, int* __restrict__ gcnt) {
    __shared__ int cnt[NBUCK];
    const int b = blockIdx.x;
    if (b < CVX_BLK) {
        int i = b * 256 + threadIdx.x;
        const int n4 = NN * DD / 4;
        for (; i < n4; i += CVX_BLK * 256) {
            float4 v = reinterpret_cast<const float4*>(x)[i];
            ushort4 o;
            o.x = f2bf(v.x); o.y = f2bf(v.y); o.z = f2bf(v.z); o.w = f2bf(v.w);
            reinterpret_cast<ushort4*>(xb)[i] = o;
            xf8[i] = pk_fp8x4(v.x, v.y, v.z, v.w);
        }
    } else if (b < CVX_BLK + CVW_BLK) {
        int t = (b - CVX_BLK) * 256 + threadIdx.x;   // 0 .. 6*16384-1
        int i = t >> 14;
        int r = t & 16383;
        const float* W = (i == 0) ? w0 : (i == 1) ? w1 : (i == 2) ? w2
                        : (i == 3) ? w3 : (i == 4) ? w4 : w5;
        int c = r >> 7, k = r & 127;
        wtall[t] = f2bf(W[k * DD + c]);
    } else {
        for (int i = threadIdx.x; i < NBUCK; i += 256) cnt[i] = 0;
        __syncthreads();
        int base = (b - CVX_BLK - CVW_BLK) * ECHUNK;
        int end = base + ECHUNK; if (end > NE) end = NE;
        for (int i = base + threadIdx.x; i < end; i += 256)
            atomicAdd(&cnt[row[i] >> 8], 1);
        __syncthreads();
        for (int i = threadIdx.x; i < NBUCK; i += 256) {
            int c = cnt[i];
            if (c) atomicAdd(&gcnt[i], c);
        }
    }
}

// ---------------- bucketed CSR build ----------------

__global__ __launch_bounds__(512) void bucket_scan(const int* __restrict__ gcnt,
                                                   int* __restrict__ gbase) {
    __shared__ int sm[512];
    int t = threadIdx.x;
    sm[t] = (t < NBUCK) ? gcnt[t] : 0;
    __syncthreads();
    for (int off = 1; off < 512; off <<= 1) {
        int add = (t >= off) ? sm[t - off] : 0;
        __syncthreads();
        sm[t] += add;
        __syncthreads();
    }
    if (t < NBUCK) gbase[t + 1] = sm[t];
    if (t == 0) gbase[0] = 0;
}

// edges packed as (col<<8)|(row&255): row-in-bucket fits 8 bits, col fits 17
__global__ __launch_bounds__(256) void bucket_scatter(const int* __restrict__ row,
                                                      const int* __restrict__ col,
                                                      const int* __restrict__ gbase,
                                                      int* __restrict__ gcursor,
                                                      unsigned int* __restrict__ ebuf) {
    __shared__ int cnt[NBUCK];
    __shared__ int base[NBUCK];
    for (int i = threadIdx.x; i < NBUCK; i += 256) cnt[i] = 0;
    __syncthreads();
    int cbase = blockIdx.x * ECHUNK;
    int cend = cbase + ECHUNK; if (cend > NE) cend = NE;
    for (int i = cbase + threadIdx.x; i < cend; i += 256)
        atomicAdd(&cnt[row[i] >> 8], 1);
    __syncthreads();
    for (int i = threadIdx.x; i < NBUCK; i += 256) {
        int c = cnt[i];
        cnt[i] = 0;
        base[i] = c ? (gbase[i] + atomicAdd(&gcursor[i], c)) : 0;
    }
    __syncthreads();
    for (int i = cbase + threadIdx.x; i < cend; i += 256) {
        int r = row[i], c = col[i];
        int b = r >> 8;
        int k = atomicAdd(&cnt[b], 1);
        ebuf[base[b] + k] = ((unsigned)c << 8) | ((unsigned)r & 255u);
    }
}

__global__ __launch_bounds__(256) void csr_build(const unsigned int* __restrict__ ebuf,
                                                 const int* __restrict__ gbase,
                                                 int* __restrict__ offs,
                                                 int* __restrict__ csr_col) {
    __shared__ int dcnt[NPB];
    __shared__ int doff[NPB];
    __shared__ int sm[NPB];
    __shared__ int stage[CAP];
    const int b = blockIdx.x;
    const int es = gbase[b], ee = gbase[b + 1];
    const int m = ee - es;
    const int t = threadIdx.x;
    const int nbase = b * NPB;

    dcnt[t] = 0;
    __syncthreads();
    for (int i = es + t; i < ee; i += 256) {
        int ln = (int)(ebuf[i] & 255u);
        atomicAdd(&dcnt[ln], 1);
    }
    __syncthreads();
    sm[t] = dcnt[t];
    __syncthreads();
    for (int off = 1; off < 256; off <<= 1) {
        int add = (t >= off) ? sm[t - off] : 0;
        __syncthreads();
        sm[t] += add;
        __syncthreads();
    }
    doff[t] = sm[t] - dcnt[t];
    int node = nbase + t;
    if (node < NN) offs[node + 1] = es + sm[t];
    if (b == 0 && t == 0) offs[0] = 0;
    dcnt[t] = 0;
    __syncthreads();

    if (m <= CAP) {
        for (int i = es + t; i < ee; i += 256) {
            unsigned e = ebuf[i];
            int ln = (int)(e & 255u);
            int k = atomicAdd(&dcnt[ln], 1);
            stage[doff[ln] + k] = (int)(e >> 8);
        }
        __syncthreads();
        for (int i = t; i < m; i += 256) csr_col[es + i] = stage[i];
    } else {
        for (int i = es + t; i < ee; i += 256) {
            unsigned e = ebuf[i];
            int ln = (int)(e & 255u);
            int k = atomicAdd(&dcnt[ln], 1);
            csr_col[es + doff[ln] + k] = (int)(e >> 8);
        }
    }
}

// ---------------- fused layer: fp8 gather-aggregate + dual GEMM + epilogue ----------------

// per 64-row tile: gather-mean fp8 neighbors (8 lanes x 16B per node) into a
// swizzled bf16 A LDS tile (16KB); H fragments load directly from global (bf16)
// into MFMA layout (issued first, hidden under gather); epilogue streams out via
// two 32-row passes through the same 16KB LDS.
__global__ __launch_bounds__(256, 6) void fused_layer(
    const unsigned short* __restrict__ hb,           // bf16 h (self term)
    const unsigned int* __restrict__ f8,             // fp8 h (gather table), dword-viewed
    const int* __restrict__ offs, const int* __restrict__ csr_col,
    const unsigned short* __restrict__ WlT, const unsigned short* __restrict__ WrT,
    const float* __restrict__ bias, float* __restrict__ out,
    unsigned short* __restrict__ hbn, unsigned int* __restrict__ f8n) {
    __shared__ uint4 smem4[1024];            // 16KB: A tile, reused as fp32 half-out tile
    char* AldsB = (char*)smem4;
    const int row0 = blockIdx.x * BM;
    const int tid = threadIdx.x;
    const int w = tid >> 6, l = tid & 63;
    const int wr = w & 1, wc = w >> 1;
    const int lrow = l & 15, lg = l >> 4;

    // 1) H fragments straight from global in MFMA layout (latency hides under gather)
    bf16x8 aH[2][4];
#pragma unroll
    for (int m = 0; m < 2; ++m) {
        int gr = row0 + wr * 32 + m * 16 + lrow;
        if (gr >= NN) gr = NN - 1;
        const unsigned short* hrow = hb + (size_t)gr * DD;
#pragma unroll
        for (int kb = 0; kb < 4; ++kb)
            aH[m][kb] = *reinterpret_cast<const bf16x8*>(hrow + kb * 32 + lg * 8);
    }

    // 2) fp8 gather-aggregate: 8 lanes per node (16B/lane), 2 rows per group
    const int grp = tid >> 3, lane = tid & 7;
    const uint4* f84 = reinterpret_cast<const uint4*>(f8);
#pragma unroll
    for (int i = 0; i < 2; ++i) {
        const int rloc = grp * 2 + i;
        const int node = row0 + rloc;
        f32x2 a[8];
#pragma unroll
        for (int k = 0; k < 8; ++k) a[k] = (f32x2){0.f, 0.f};
        float inv = 0.0f;
        if (node < NN) {
            int s = offs[node], e = offs[node + 1];
            int p = s;
            for (; p + 8 <= e; p += 8) {
                uint4 v[8];
#pragma unroll
                for (int q = 0; q < 8; ++q)
                    v[q] = f84[(size_t)csr_col[p + q] * 8 + lane];
#pragma unroll
                for (int q = 0; q < 8; ++q) {
                    a[0] += upk_fp8_lo(v[q].x); a[1] += upk_fp8_hi(v[q].x);
                    a[2] += upk_fp8_lo(v[q].y); a[3] += upk_fp8_hi(v[q].y);
                    a[4] += upk_fp8_lo(v[q].z); a[5] += upk_fp8_hi(v[q].z);
                    a[6] += upk_fp8_lo(v[q].w); a[7] += upk_fp8_hi(v[q].w);
                }
            }
            for (; p < e; ++p) {
                uint4 v = f84[(size_t)csr_col[p] * 8 + lane];
                a[0] += upk_fp8_lo(v.x); a[1] += upk_fp8_hi(v.x);
                a[2] += upk_fp8_lo(v.y); a[3] += upk_fp8_hi(v.y);
                a[4] += upk_fp8_lo(v.z); a[5] += upk_fp8_hi(v.z);
                a[6] += upk_fp8_lo(v.w); a[7] += upk_fp8_hi(v.w);
            }
            inv = (e > s) ? (1.0f / (float)(e - s)) : 0.0f;
        }
        uint4 o0, o1;
        o0.x = packbf(a[0][0] * inv, a[0][1] * inv);
        o0.y = packbf(a[1][0] * inv, a[1][1] * inv);
        o0.z = packbf(a[2][0] * inv, a[2][1] * inv);
        o0.w = packbf(a[3][0] * inv, a[3][1] * inv);
        o1.x = packbf(a[4][0] * inv, a[4][1] * inv);
        o1.y = packbf(a[5][0] * inv, a[5][1] * inv);
        o1.z = packbf(a[6][0] * inv, a[6][1] * inv);
        o1.w = packbf(a[7][0] * inv, a[7][1] * inv);
        const int sw = (rloc & 7) << 4;
        const int rbase = rloc << 8;
        *reinterpret_cast<uint4*>(AldsB + rbase + ((lane * 32) ^ sw)) = o0;
        *reinterpret_cast<uint4*>(AldsB + rbase + ((lane * 32 + 16) ^ sw)) = o1;
    }
    __syncthreads();

    // 3) MFMA: acc = A@Wl + H@Wr
    f32x4 acc[2][4];
#pragma unroll
    for (int m = 0; m < 2; ++m)
#pragma unroll
        for (int n = 0; n < 4; ++n) acc[m][n] = (f32x4){0.f, 0.f, 0.f, 0.f};

    float bv[4];
#pragma unroll
    for (int n = 0; n < 4; ++n) bv[n] = bias[wc * 64 + n * 16 + lrow];

#pragma unroll
    for (int kb = 0; kb < 4; ++kb) {
        const int kbyte = kb * 64 + lg * 16;
        bf16x8 aA[2];
#pragma unroll
        for (int m = 0; m < 2; ++m) {
            int rloc = wr * 32 + m * 16 + lrow;
            int off = (rloc << 8) + kbyte;
            off ^= (rloc & 7) << 4;
            aA[m] = *reinterpret_cast<const bf16x8*>(AldsB + off);
        }
        bf16x8 bL[4], bR[4];
#pragma unroll
        for (int n = 0; n < 4; ++n) {
            size_t woff = ((size_t)(wc * 64 + n * 16 + lrow) << 7) + kb * 32 + lg * 8;
            bL[n] = *reinterpret_cast<const bf16x8*>(WlT + woff);
            bR[n] = *reinterpret_cast<const bf16x8*>(WrT + woff);
        }
#pragma unroll
        for (int m = 0; m < 2; ++m)
#pragma unroll
            for (int n = 0; n < 4; ++n) {
                acc[m][n] = __builtin_amdgcn_mfma_f32_16x16x32_bf16(aA[m], bL[n], acc[m][n], 0, 0, 0);
                acc[m][n] = __builtin_amdgcn_mfma_f32_16x16x32_bf16(aH[m][kb], bR[n], acc[m][n], 0, 0, 0);
            }
    }

    // 4) epilogue: two 32-row passes through the 16KB LDS, coalesced streams
    __syncthreads();
    float* otile = (float*)smem4;
#pragma unroll
    for (int half = 0; half < 2; ++half) {
        if (wr == half) {
#pragma unroll
            for (int m = 0; m < 2; ++m) {
                int rb = m * 16 + lg * 4;
#pragma unroll
                for (int n = 0; n < 4; ++n) {
                    int c = wc * 64 + n * 16 + lrow;
#pragma unroll
                    for (int j = 0; j < 4; ++j)
                        otile[(rb + j) * DD + c] = fmaxf(acc[m][n][j] + bv[n], 0.0f);
                }
            }
        }
        __syncthreads();
        const f32x4* t4 = (const f32x4*)smem4;
#pragma unroll
        for (int it = 0; it < 4; ++it) {
            int idx = it * 256 + tid;        // 1024 f32x4 units in 32x128 tile
            int r = idx >> 5;
            int gr = row0 + half * 32 + r;
            if (gr < NN) {
                f32x4 v = t4[idx];
                __builtin_nontemporal_store(v, (f32x4*)out + (size_t)gr * 32 + (idx & 31));
                if (hbn) {
                    uint2 pk;
                    pk.x = packbf(v[0], v[1]);
                    pk.y = packbf(v[2], v[3]);
                    *((uint2*)hbn + (size_t)gr * 32 + (idx & 31)) = pk;
                    f8n[(size_t)gr * 32 + (idx & 31)] = pk_fp8x4(v[0], v[1], v[2], v[3]);
                }
            }
        }
        __syncthreads();
    }
}

extern "C" void kernel_launch(void* const* d_in, const int* in_sizes, int n_in,
                              void* d_out, int out_size, void* d_ws, size_t ws_size,
                              hipStream_t stream) {
    const float* x = (const float*)d_in[0];
    const int* ei = (const int*)d_in[1];
    const int* row = ei;        // dst
    const int* col = ei + NE;   // src
    const float* Wl[3] = {(const float*)d_in[2], (const float*)d_in[5], (const float*)d_in[8]};
    const float* Wr[3] = {(const float*)d_in[3], (const float*)d_in[6], (const float*)d_in[9]};
    const float* bb[3] = {(const float*)d_in[4], (const float*)d_in[7], (const float*)d_in[10]};
    float* out = (float*)d_out;

    char* ws = (char*)d_ws;
    auto carve = [&](size_t bytes) {
        char* p = ws;
        ws += (bytes + 255) & ~(size_t)255;
        return p;
    };
    unsigned short* buf0 = (unsigned short*)carve((size_t)NN * DD * 2);
    unsigned short* buf1 = (unsigned short*)carve((size_t)NN * DD * 2);
    unsigned int* f8a = (unsigned int*)carve((size_t)NN * DD);      // fp8 tables, 12.8 MB each
    unsigned int* f8b = (unsigned int*)carve((size_t)NN * DD);
    unsigned short* wtall = (unsigned short*)carve((size_t)6 * DD * DD * 2);
    int* gcnt    = (int*)carve((size_t)2 * NBUCK * sizeof(int));  // gcnt + gcursor
    int* gcursor = gcnt + NBUCK;
    int* gbase   = (int*)carve((size_t)(NBUCK + 1) * sizeof(int));
    int* offs    = (int*)carve((size_t)(NN + 1) * sizeof(int));
    unsigned int* ebuf = (unsigned int*)carve((size_t)NE * sizeof(unsigned int)); // 6.4 MB
    int* csr_col = (int*)carve((size_t)NE * sizeof(int));         // 6.4 MB

    hipMemsetAsync(gcnt, 0, (size_t)2 * NBUCK * sizeof(int), stream);

    prep_kernel<<<CVX_BLK + CVW_BLK + NBLK_PART, 256, 0, stream>>>(
        x, buf0, f8a, Wl[0], Wr[0], Wl[1], Wr[1], Wl[2], Wr[2], wtall, row, gcnt);
    bucket_scan<<<1, 512, 0, stream>>>(gcnt, gbase);
    bucket_scatter<<<NBLK_PART, 256, 0, stream>>>(row, col, gbase, gcursor, ebuf);
    csr_build<<<NBUCK, 256, 0, stream>>>(ebuf, gbase, offs, csr_col);

    const int ngrid = (NN + BM - 1) / BM;   // 1563

    unsigned short* hin = buf0;
    unsigned short* hout = buf1;
    unsigned int* f8in = f8a;
    unsigned int* f8out = f8b;
    for (int lyr = 0; lyr < 3; ++lyr) {
        float* o = out + (size_t)lyr * NN * DD;
        fused_layer<<<ngrid, 256, 0, stream>>>(
            hin, f8in, offs, csr_col,
            wtall + (size_t)2 * lyr * DD * DD, wtall + (size_t)(2 * lyr + 1) * DD * DD,
            bb[lyr], o,
            (lyr < 2) ? hout : (unsigned short*)nullptr,
            (lyr < 2) ? f8out : (unsigned int*)nullptr);
        unsigned short* t = hin; hin = hout; hout = t;
        unsigned int* t8 = f8in; f8in = f8out; f8out = t8;
    }
}